// Round 12
// baseline (239.496 us; speedup 1.0000x reference)
//
#include <hip/hip_runtime.h>

#define PI_F 3.14159265358979323846f

typedef short bf16x8 __attribute__((ext_vector_type(8)));
typedef float f32x4 __attribute__((ext_vector_type(4)));

#define MFMA16(acc, a, b) \
  acc = __builtin_amdgcn_mfma_f32_16x16x32_bf16(a, b, acc, 0, 0, 0)

// ---------------- workspace layout (float offsets) ----------------
// WS_SPEC region (16 MB) is dead after k_proj_in -> FFT-conv buffers:
#define WS_RR     0u          // 129*32*256 = 1,056,768   R spectrum (re)
#define WS_RI     1056768u    //                          R spectrum (im)
#define WS_VR     2113536u    // 129*32*32  = 132,096     V spectrum (re)
#define WS_VI     2245632u    //                          V spectrum (im)
#define WS_YR     2377728u    // 129*32*256 = 1,056,768   Y spectrum (re); ends 3,434,496
#define WS_SPEC   0u          // 32*128*1024 [b][t][k] (spec lives here until proj_in)
#define WS_H0     4194304u    // 32*32*128    [b][o][t]
#define WS_ACC    4325376u    // 32*128*32    [b][t][o]
#define WS_V      4456448u    // 32*32*128    [b][c][t]; k_prep stashes chain-weight
                              // bf16 packs in the first 16384 floats (consumed by
                              // k_chain before k_sparse_dense writes v here)
#define WS_WTIN   4587520u    // 1024*32      [k][o]
#define WS_WST    4620288u    // 32*256       [m][o2]
#define WS_WDT    4628480u    // 256*32       [o2][c]
#define WS_FRAMES 4636672u    // 32*32*2048   [c][f][j]; dead after k_rfft ->
                              //   Y spectrum (im) lives here for k_cgemm/k_yifft
#define WS_YI     4636672u    // 129*32*256 = 1,056,768
// total < 7782400 floats = ~29.7 MB

// ---- 2048-pt complex DIT FFT, input already in bit-reversed order, 256 thr ----
__device__ __forceinline__ void fft2048_stages(float2* buf, int tid) {
  for (int stage = 0; stage < 11; ++stage) {
    int half = 1 << stage;
    float base = -PI_F / (float)half;   // -2*pi/len
    for (int t = tid; t < 1024; t += 256) {
      int j  = t & (half - 1);
      int i0 = ((t >> stage) << (stage + 1)) + j;
      int i1 = i0 + half;
      float s, c;
      __sincosf(base * (float)j, &s, &c);   // e^{-i*2pi/len*j} = c + i*s
      float2 u = buf[i0];
      float2 w = buf[i1];
      float tr = c * w.x - s * w.y;
      float ti = c * w.y + s * w.x;
      buf[i0] = make_float2(u.x + tr, u.y + ti);
      buf[i1] = make_float2(u.x - tr, u.y - ti);
    }
    __syncthreads();
  }
}

// ---- 256-pt complex DIT FFT over NROWS rows, bit-reversed input, 256 thr ----
// sgn = -1: forward (e^{-i...}); sgn = +1: inverse butterflies (no 1/N scale).
template<int NROWS>
__device__ __forceinline__ void fft256_rows(float2 (*buf)[256], int tid, float sgn) {
  for (int stage = 0; stage < 8; ++stage) {
    int half = 1 << stage;
    float base = sgn * PI_F / (float)half;
    for (int t = tid; t < NROWS * 128; t += 256) {
      int row = t >> 7, tt = t & 127;
      int j  = tt & (half - 1);
      int i0 = ((tt >> stage) << (stage + 1)) + j;
      int i1 = i0 + half;
      float s, c;
      __sincosf(base * (float)j, &s, &c);
      float2 u = buf[row][i0];
      float2 w = buf[row][i1];
      float tr = c * w.x - s * w.y;
      float ti = c * w.y + s * w.x;
      buf[row][i0] = make_float2(u.x + tr, u.y + ti);
      buf[row][i1] = make_float2(u.x - tr, u.y - ti);
    }
    __syncthreads();
  }
}

// ---------------- fused FFT kernel: STFT pairs + resonance-frame pairs ----------------
__global__ __launch_bounds__(256) void k_fft(const float* __restrict__ audio,
                                             const float* __restrict__ resin,
                                             float* __restrict__ spec,
                                             float* __restrict__ frames) {
  __shared__ float2 buf[2048];
  int blk = blockIdx.x;
  if (blk < 2048) {
    int b  = blk >> 6;
    int f0 = (blk & 63) * 2;      // frames f0, f0+1
    for (int j = threadIdx.x; j < 2048; j += 256) {
      float h = 0.5f - 0.5f * __cosf(0.0030679615757712823f * (float)j); // 2pi/2048
      int i1 = f0 * 256 + j;
      int i2 = i1 + 256;
      float a1 = (i1 < 32768) ? audio[b * 32768 + i1] : 0.f;
      float a2 = (i2 < 32768) ? audio[b * 32768 + i2] : 0.f;
      buf[__brev((unsigned)j) >> 21] = make_float2(a1 * h, a2 * h);
    }
    __syncthreads();
    fft2048_stages(buf, threadIdx.x);
    const float scale = 0.5f * 0.022097086912079608f;  // 0.5 / sqrt(2048)
    for (int k = threadIdx.x; k < 1024; k += 256) {
      float2 zk = buf[k];
      float2 zn = buf[(2048 - k) & 2047];
      float f1r = zk.x + zn.x, f1i = zk.y - zn.y;
      float f2r = zk.y + zn.y, f2i = zk.x - zn.x;
      spec[(b * 128 + f0) * 1024 + k]     = sqrtf(f1r * f1r + f1i * f1i) * scale;
      spec[(b * 128 + f0 + 1) * 1024 + k] = sqrtf(f2r * f2r + f2i * f2i) * scale;
    }
  } else {
    int r = blk - 2048;           // 0..511
    int c = r >> 4;
    int g = r & 15;               // frames 2g (exp 2g+1), 2g+1 (exp 2g+2)
    float e1 = (float)(2 * g + 1);
    for (int k = threadIdx.x; k < 2048; k += 256) {
      int kk = (k <= 1024) ? k : 2048 - k;   // Hermitian (real) extension
      float cv = resin[c * 1025 + kk];
      cv = fminf(fmaxf(cv, 0.f), 0.9999f);
      float m1 = __powf(cv, e1);
      float m2 = m1 * cv;
      buf[__brev((unsigned)k) >> 21] = make_float2(m1, m2);
    }
    __syncthreads();
    fft2048_stages(buf, threadIdx.x);
    for (int j = threadIdx.x; j < 2048; j += 256) {
      float h  = 0.5f - 0.5f * __cosf(0.0030679615757712823f * (float)j);
      float sc = h * (1.f / 2048.f);
      float2 z = buf[j];
      frames[(c * 32 + 2 * g) * 2048 + j]     = z.x * sc;
      frames[(c * 32 + 2 * g + 1) * 2048 + j] = z.y * sc;
    }
  }
}

// ---------------- weight transposes + chain-weight bf16 hi/lo packs ----------------
__global__ __launch_bounds__(256) void k_prep(const float* __restrict__ Win,
                                              const float* __restrict__ Ws,
                                              const float* __restrict__ Wd,
                                              const float* __restrict__ bwIn,
                                              float* __restrict__ WT,
                                              float* __restrict__ WsT,
                                              float* __restrict__ WdT,
                                              short* __restrict__ Whg,
                                              short* __restrict__ Wlg) {
  int i = blockIdx.x * 256 + threadIdx.x;
  if (i < 32768) { int o = i >> 10, k = i & 1023; WT[k * 32 + o] = Win[i]; }
  if (i < 8192)  { int o2 = i >> 5, m = i & 31;   WsT[m * 256 + o2] = Ws[i]; }
  if (i < 8192)  { int c = i >> 8, o2 = i & 255;  WdT[o2 * 32 + c] = Wd[i]; }
  if (i < 16384) {
    // i = ((s*32+o)*32+m)*2 + w
    int w = i & 1, m = (i >> 1) & 31, o = (i >> 6) & 31, s = i >> 11;
    float val = bwIn[i];
    unsigned bits = __float_as_uint(val);
    float rem = val - __uint_as_float(bits & 0xffff0000u);
    int row = (s * 2 + w) * 32 + o;
    Whg[row * 32 + m] = (short)(bits >> 16);
    Wlg[row * 32 + m] = (short)(__float_as_uint(rem) >> 16);
  }
}

// ---------------- proj_in: h0[b,o,t] = sum_k WT[k][o]*spec[b,t,k] + bias ----------------
__global__ __launch_bounds__(256) void k_proj_in(const float* __restrict__ spec,
                                                 const float* __restrict__ WT,
                                                 const float* __restrict__ bias,
                                                 float* __restrict__ h0) {
  __shared__ float specL[8][1024];
  __shared__ float red[32][8][8];   // [o][tt][p]
  int b  = blockIdx.x >> 4;
  int t0 = (blockIdx.x & 15) * 8;
  for (int i = threadIdx.x; i < 8192; i += 256) {
    int tt = i >> 10, k = i & 1023;
    specL[tt][k] = spec[(b * 128 + t0 + tt) * 1024 + k];
  }
  __syncthreads();
  int o = threadIdx.x & 31, p = threadIdx.x >> 5;
  float part[8] = {0.f,0.f,0.f,0.f,0.f,0.f,0.f,0.f};
  for (int i = 0; i < 128; ++i) {
    int k = p * 128 + ((i + p * 4) & 127);   // stagger: conflict-free banks across p
    float w = WT[k * 32 + o];
#pragma unroll
    for (int tt = 0; tt < 8; ++tt) part[tt] += w * specL[tt][k];
  }
#pragma unroll
  for (int tt = 0; tt < 8; ++tt) red[o][tt][p] = part[tt];
  __syncthreads();
  int oo = threadIdx.x >> 3, tt2 = threadIdx.x & 7;
  float s = bias[oo];
#pragma unroll
  for (int p2 = 0; p2 < 8; ++p2) s += red[oo][tt2][p2];
  h0[b * 4096 + oo * 128 + t0 + tt2] = s;
}

// ---------------- 8-block anticausal chain as per-step MFMA GEMM pairs ----------------
__global__ __launch_bounds__(1024) void k_chain(const float* __restrict__ h0,
                                                const short* __restrict__ Whg,
                                                const short* __restrict__ Wlg,
                                                const float* __restrict__ bb,
                                                float* __restrict__ accout) {
  __shared__ __align__(16) short Hh[192 * 40];   // rows stride 40 bf16 (80 B)
  __shared__ __align__(16) short Hl[192 * 40];
  __shared__ float Hf[128 * 33];                 // fp32 H for exact residual
  __shared__ float bL[256];
  __shared__ float red[16];
  int b = blockIdx.x, tid = threadIdx.x;

  for (int i = tid; i < 4096; i += 1024) {
    int t = i & 127;                 // h0 layout [o][t]
    int o = i >> 7;
    float val = h0[b * 4096 + i];
    Hf[t * 33 + o] = val;
    unsigned bits = __float_as_uint(val);
    float rem = val - __uint_as_float(bits & 0xffff0000u);
    Hh[t * 40 + o] = (short)(bits >> 16);
    Hl[t * 40 + o] = (short)(__float_as_uint(rem) >> 16);
  }
  for (int i = tid; i < 64 * 40; i += 1024) {    // zero pad rows 128..191
    Hh[128 * 40 + i] = 0;
    Hl[128 * 40 + i] = 0;
  }
  if (tid < 256) bL[tid] = bb[tid];
  __syncthreads();

  int wave = tid >> 6, lane = tid & 63;
  int quad = lane >> 4, l15 = lane & 15;
  int t0 = (wave & 7) * 16, o0 = (wave >> 3) * 16;
  int tD = t0 + quad * 4;          // D rows tD..tD+3
  int oD = o0 + l15;               // D col

  const bf16x8* Hh8 = (const bf16x8*)Hh;   // unit = row*5 + quad (40 bf16 = 5 units)
  const bf16x8* Hl8 = (const bf16x8*)Hl;
  const bf16x8* Wh8 = (const bf16x8*)Whg;  // unit = row*4 + quad (32 bf16 = 4 units)
  const bf16x8* Wl8 = (const bf16x8*)Wlg;

  float accsum[4] = {0.f, 0.f, 0.f, 0.f};
  const int DIL[8] = {1, 2, 4, 8, 16, 32, 64, 1};

#pragma unroll
  for (int s = 0; s < 8; ++s) {
    int arow = t0 + l15;
    int frow = arow + DIL[s];        // <= 191, pad rows give zeros
    bf16x8 Ah = Hh8[arow * 5 + quad];
    bf16x8 Al = Hl8[arow * 5 + quad];
    bf16x8 Fh = Hh8[frow * 5 + quad];
    bf16x8 Fl = Hl8[frow * 5 + quad];
    int w0row = ((s * 2 + 0) * 32 + oD) * 4 + quad;
    int w1row = ((s * 2 + 1) * 32 + oD) * 4 + quad;
    bf16x8 B0h = Wh8[w0row], B0l = Wl8[w0row];
    bf16x8 B1h = Wh8[w1row], B1l = Wl8[w1row];
    float bias = bL[s * 32 + oD];
    f32x4 acc = {bias, bias, bias, bias};
    MFMA16(acc, Ah, B0h); MFMA16(acc, Ah, B0l); MFMA16(acc, Al, B0h);
    MFMA16(acc, Fh, B1h); MFMA16(acc, Fh, B1l); MFMA16(acc, Fl, B1h);
    float hnew[4], lmax = 0.f;
#pragma unroll
    for (int r = 0; r < 4; ++r) {
      float sv = acc[r];
      sv = (sv > 0.f) ? sv : 0.2f * sv;       // leaky_relu 0.2
      sv += Hf[(tD + r) * 33 + oD];           // residual (exact fp32)
      hnew[r] = sv;
      lmax = fmaxf(lmax, fabsf(sv));
    }
#pragma unroll
    for (int off = 32; off > 0; off >>= 1)
      lmax = fmaxf(lmax, __shfl_down(lmax, off, 64));
    if (lane == 0) red[wave] = lmax;
    __syncthreads();                 // red visible; all H reads of this step done
    float mx = red[0];
#pragma unroll
    for (int i = 1; i < 16; ++i) mx = fmaxf(mx, red[i]);
    float nm = 1.f / (mx + 1e-8f);
#pragma unroll
    for (int r = 0; r < 4; ++r) {
      float hv = hnew[r] * nm;
      accsum[r] += hv;
      int t = tD + r;
      Hf[t * 33 + oD] = hv;
      unsigned bits = __float_as_uint(hv);
      float rem = hv - __uint_as_float(bits & 0xffff0000u);
      Hh[t * 40 + oD] = (short)(bits >> 16);
      Hl[t * 40 + oD] = (short)(__float_as_uint(rem) >> 16);
    }
    __syncthreads();                 // new H visible for next step
  }
#pragma unroll
  for (int r = 0; r < 4; ++r)
    accout[b * 4096 + (tD + r) * 32 + oD] = accsum[r];
}

// ---------------- sparse (relu proj 32->256, to d_out) + dense (256->32, to ws) ----------------
__global__ __launch_bounds__(256) void k_sparse_dense(const float* __restrict__ acc,
                                                      const float* __restrict__ WsT,
                                                      const float* __restrict__ bs,
                                                      const float* __restrict__ WdT,
                                                      const float* __restrict__ bd,
                                                      float* __restrict__ out_sparse,
                                                      float* __restrict__ v) {
  __shared__ float accL[32];
  __shared__ float sL[256];
  __shared__ float red[8][32];
  int b = blockIdx.x >> 7, t = blockIdx.x & 127;
  int tid = threadIdx.x;
  if (tid < 32) accL[tid] = acc[b * 4096 + t * 32 + tid];
  __syncthreads();
  float s = bs[tid];
  for (int m = 0; m < 32; ++m) s += WsT[m * 256 + tid] * accL[m];
  s = fmaxf(s, 0.f);
  out_sparse[b * 32768 + tid * 128 + t] = s;
  sL[tid] = s;
  __syncthreads();
  int c = tid & 31, p = tid >> 5;
  float part = 0.f;
  for (int j = 0; j < 32; ++j) {
    int o2 = p * 32 + j;
    part += WdT[o2 * 32 + c] * sL[o2];
  }
  red[p][c] = part;
  __syncthreads();
  if (tid < 32) {
    float vv = bd[tid];
    for (int p2 = 0; p2 < 8; ++p2) vv += red[p2][tid];
    v[b * 4096 + tid * 128 + t] = vv;
  }
}

// ---------------- R spectrum: overlap-add (fused) + 256-pt FFT along u ----------------
// res[c, u*256+r] sequences over u (zero-padded to 256). Block = (c, 32-r group).
// Rr/Ri[(k*32+c)*256 + r], k in [0,129) (Hermitian: input real).
__global__ __launch_bounds__(256) void k_rfft(const float* __restrict__ frames,
                                              float* __restrict__ Rr,
                                              float* __restrict__ Ri) {
  __shared__ float2 buf[32][256];   // 64 KB
  int c = blockIdx.x >> 3, rg = blockIdx.x & 7;
  for (int t = threadIdx.x; t < 4096; t += 256) {
    int u = t >> 5, rr = t & 31;
    int s = u * 256 + rg * 32 + rr;
    int g = s >> 10, j0 = s & 1023;
    float val = frames[(c * 32 + g) * 2048 + j0];
    if (g > 0) val += frames[(c * 32 + g - 1) * 2048 + j0 + 1024];
    int bi = __brev((unsigned)u) >> 24;      // u<128 -> bi even; bi|1 = brev(u+128)
    buf[rr][bi]     = make_float2(val, 0.f);
    buf[rr][bi | 1] = make_float2(0.f, 0.f);
  }
  __syncthreads();
  fft256_rows<32>(buf, threadIdx.x, -1.f);
  for (int t = threadIdx.x; t < 129 * 32; t += 256) {
    int k = t >> 5, rr = t & 31;
    int idx = (k * 32 + c) * 256 + rg * 32 + rr;
    Rr[idx] = buf[rr][k].x;
    Ri[idx] = buf[rr][k].y;
  }
}

// ---------------- V spectrum: 256-pt FFT of v[b,c,:] (zero-padded) ----------------
// Block = (b, c-half). Vr/Vi[(k*32+b)*32 + c], k in [0,129).
__global__ __launch_bounds__(256) void k_vfft(const float* __restrict__ v,
                                              float* __restrict__ Vr,
                                              float* __restrict__ Vi) {
  __shared__ float2 buf[16][256];   // 32 KB
  int b = blockIdx.x >> 1, ch = blockIdx.x & 1;
  for (int t = threadIdx.x; t < 2048; t += 256) {
    int c2 = t >> 7, u = t & 127;
    float val = v[b * 4096 + (ch * 16 + c2) * 128 + u];
    int bi = __brev((unsigned)u) >> 24;
    buf[c2][bi]     = make_float2(val, 0.f);
    buf[c2][bi | 1] = make_float2(0.f, 0.f);
  }
  __syncthreads();
  fft256_rows<16>(buf, threadIdx.x, -1.f);
  for (int t = threadIdx.x; t < 129 * 16; t += 256) {
    int k = t >> 4, c2 = t & 15;
    int idx = (k * 32 + b) * 32 + ch * 16 + c2;
    Vr[idx] = buf[c2][k].x;
    Vi[idx] = buf[c2][k].y;
  }
}

// ---------------- per-frequency complex GEMM: Y[b,r] = sum_c V[b,c] * R[c,r] ----------------
// Block = (k, r-half). V tile (32x32 cplx) in LDS (broadcast reads); R streamed
// coalesced; each thread owns 16 b x 1 r. No atomics.
__global__ __launch_bounds__(256) void k_cgemm(const float* __restrict__ Vr,
                                               const float* __restrict__ Vi,
                                               const float* __restrict__ Rr,
                                               const float* __restrict__ Ri,
                                               float* __restrict__ Yr,
                                               float* __restrict__ Yi) {
  __shared__ float2 Vs[32][32];     // 8 KB
  int k = blockIdx.x >> 1, rh = blockIdx.x & 1;
  for (int t = threadIdx.x; t < 1024; t += 256)
    Vs[t >> 5][t & 31] = make_float2(Vr[k * 1024 + t], Vi[k * 1024 + t]);
  __syncthreads();
  int r = rh * 128 + (threadIdx.x & 127);
  int half = threadIdx.x >> 7;
  float yre[16], yim[16];
#pragma unroll
  for (int i = 0; i < 16; ++i) { yre[i] = 0.f; yim[i] = 0.f; }
  for (int c = 0; c < 32; ++c) {
    float rrv = Rr[(k * 32 + c) * 256 + r];
    float riv = Ri[(k * 32 + c) * 256 + r];
#pragma unroll
    for (int bbv = 0; bbv < 16; ++bbv) {
      float2 vc = Vs[half * 16 + bbv][c];   // wave-uniform -> LDS broadcast
      yre[bbv] += vc.x * rrv - vc.y * riv;
      yim[bbv] += vc.x * riv + vc.y * rrv;
    }
  }
#pragma unroll
  for (int bbv = 0; bbv < 16; ++bbv) {
    int b = half * 16 + bbv;
    Yr[(k * 32 + b) * 256 + r] = yre[bbv];
    Yi[(k * 32 + b) * 256 + r] = yim[bbv];
  }
}

// ---------------- inverse 256-pt FFT over k -> y (writes EVERY y element once) ----------------
// Block = (b, 32-r group). Hermitian reconstruction for k in (128,256).
__global__ __launch_bounds__(256) void k_yifft(const float* __restrict__ Yr,
                                               const float* __restrict__ Yi,
                                               float* __restrict__ y) {
  __shared__ float2 buf[32][256];   // 64 KB
  int b = blockIdx.x >> 3, rg = blockIdx.x & 7;
  int r0 = rg * 32;
  for (int t = threadIdx.x; t < 8192; t += 256) {
    int k = t >> 5, rr = t & 31;
    float re, im;
    if (k <= 128) {
      re = Yr[(k * 32 + b) * 256 + r0 + rr];
      im = Yi[(k * 32 + b) * 256 + r0 + rr];
    } else {
      int kk = 256 - k;
      re =  Yr[(kk * 32 + b) * 256 + r0 + rr];
      im = -Yi[(kk * 32 + b) * 256 + r0 + rr];
    }
    buf[rr][__brev((unsigned)k) >> 24] = make_float2(re, im);
  }
  __syncthreads();
  fft256_rows<32>(buf, threadIdx.x, 1.f);    // inverse butterflies
  const float inv = 1.f / 256.f;
  for (int t = threadIdx.x; t < 4096; t += 256) {
    int q = t >> 5, rr = t & 31;
    y[b * 32768 + q * 256 + r0 + rr] = buf[rr][q].x * inv;
  }
}

extern "C" void kernel_launch(void* const* d_in, const int* in_sizes, int n_in,
                              void* d_out, int out_size, void* d_ws, size_t ws_size,
                              hipStream_t stream) {
  const float* audio = (const float*)d_in[0];
  const float* Win   = (const float*)d_in[1];
  const float* bin   = (const float*)d_in[2];
  const float* bw    = (const float*)d_in[3];
  const float* bb    = (const float*)d_in[4];
  const float* Ws    = (const float*)d_in[5];
  const float* bs    = (const float*)d_in[6];
  const float* Wd    = (const float*)d_in[7];
  const float* bd    = (const float*)d_in[8];
  const float* reson = (const float*)d_in[9];

  float* out = (float*)d_out;           // [0,1048576) = y ; [1048576,2097152) = sparse
  float* ws  = (float*)d_ws;

  float* spec   = ws + WS_SPEC;
  float* h0     = ws + WS_H0;
  float* accb   = ws + WS_ACC;
  float* vbuf   = ws + WS_V;
  float* WT     = ws + WS_WTIN;
  float* WsT    = ws + WS_WST;
  float* WdT    = ws + WS_WDT;
  float* frames = ws + WS_FRAMES;
  // chain-weight packs live in WS_V until k_sparse_dense overwrites it (after k_chain)
  short* Whg = (short*)(ws + WS_V);                // 16384 bf16 = 32 KB
  short* Wlg = (short*)(ws + WS_V + 8192u);        // 16384 bf16 = 32 KB
  // FFT-conv buffers in the spec region (dead after k_proj_in) + frames region
  float* Rr = ws + WS_RR;
  float* Ri = ws + WS_RI;
  float* Vr = ws + WS_VR;
  float* Vi = ws + WS_VI;
  float* Yr = ws + WS_YR;
  float* Yi = ws + WS_YI;   // frames region, dead after k_rfft

  k_prep<<<128, 256, 0, stream>>>(Win, Ws, Wd, bw, WT, WsT, WdT, Whg, Wlg);
  k_fft<<<2560, 256, 0, stream>>>(audio, reson, spec, frames);
  k_proj_in<<<512, 256, 0, stream>>>(spec, WT, bin, h0);
  k_rfft<<<256, 256, 0, stream>>>(frames, Rr, Ri);          // spec region now free
  k_chain<<<32, 1024, 0, stream>>>(h0, Whg, Wlg, bb, accb);
  k_sparse_dense<<<4096, 256, 0, stream>>>(accb, WsT, bs, WdT, bd, out + 1048576, vbuf);
  k_vfft<<<64, 256, 0, stream>>>(vbuf, Vr, Vi);
  k_cgemm<<<258, 256, 0, stream>>>(Vr, Vi, Rr, Ri, Yr, Yi);
  k_yifft<<<256, 256, 0, stream>>>(Yr, Yi, out);            // writes all of y: no memset
}

// Round 13
// 223.189 us; speedup vs baseline: 1.0731x; 1.0731x over previous
//
#include <hip/hip_runtime.h>

#define PI_F 3.14159265358979323846f

typedef short bf16x8 __attribute__((ext_vector_type(8)));
typedef float f32x4 __attribute__((ext_vector_type(4)));

#define MFMA16(acc, a, b) \
  acc = __builtin_amdgcn_mfma_f32_16x16x32_bf16(a, b, acc, 0, 0, 0)

// LDS skew: maps bit-reversal strides (multiples of 32) onto distinct banks.
#define SK(i) ((i) + ((i) >> 5))

// ---------------- workspace layout (float offsets) ----------------
#define WS_RR     0u          // 129*32*256   R spectrum (re)   [spec region]
#define WS_RI     1056768u    //              R spectrum (im)
#define WS_VR     2113536u    // 129*32*32    V spectrum (re)
#define WS_VI     2245632u    //              V spectrum (im)
#define WS_YR     2377728u    // 129*32*256   Y spectrum (re); ends 3,434,496
#define WS_SPEC   0u          // 32*128*1024 [b][t][k] (spec lives here until proj_in)
#define WS_H0     4194304u    // 32*32*128    [b][o][t]
#define WS_ACC    4325376u    // 32*128*32    [b][t][o]
#define WS_V      4456448u    // 32*32*128    [b][c][t]; k_prep stashes chain-weight
                              // bf16 packs in the first 16384 floats
#define WS_WTIN   4587520u    // 1024*32      [k][o]
#define WS_WST    4620288u    // 32*256       [m][o2]
#define WS_WDT    4628480u    // 256*32       [o2][c]
#define WS_FRAMES 4636672u    // 32*32*2048   [c][f][j]; dead after k_rfft -> Y im
#define WS_YI     4636672u    // 129*32*256
// total < 7782400 floats = ~29.7 MB

// ---- 2048-pt complex DIT FFT, skewed LDS, input bit-rev placed, 256 thr ----
__device__ __forceinline__ void fft2048_stages(float2* buf, int tid) {
  for (int stage = 0; stage < 11; ++stage) {
    int half = 1 << stage;
    float base = -PI_F / (float)half;   // -2*pi/len
    for (int t = tid; t < 1024; t += 256) {
      int j  = t & (half - 1);
      int i0 = ((t >> stage) << (stage + 1)) + j;
      int i1 = i0 + half;
      float s, c;
      __sincosf(base * (float)j, &s, &c);   // e^{-i*2pi/len*j} = c + i*s
      float2 u = buf[SK(i0)];
      float2 w = buf[SK(i1)];
      float tr = c * w.x - s * w.y;
      float ti = c * w.y + s * w.x;
      buf[SK(i0)] = make_float2(u.x + tr, u.y + ti);
      buf[SK(i1)] = make_float2(u.x - tr, u.y - ti);
    }
    __syncthreads();
  }
}

// ---- 256-pt complex DIT FFT over NROWS rows, skewed cols, bit-rev input ----
// sgn = -1: forward; sgn = +1: inverse butterflies (no 1/N scale).
template<int NROWS>
__device__ __forceinline__ void fft256_rows(float2 (*buf)[264], int tid, float sgn) {
  for (int stage = 0; stage < 8; ++stage) {
    int half = 1 << stage;
    float base = sgn * PI_F / (float)half;
    for (int t = tid; t < NROWS * 128; t += 256) {
      int row = t >> 7, tt = t & 127;
      int j  = tt & (half - 1);
      int i0 = ((tt >> stage) << (stage + 1)) + j;
      int i1 = i0 + half;
      float s, c;
      __sincosf(base * (float)j, &s, &c);
      float2 u = buf[row][SK(i0)];
      float2 w = buf[row][SK(i1)];
      float tr = c * w.x - s * w.y;
      float ti = c * w.y + s * w.x;
      buf[row][SK(i0)] = make_float2(u.x + tr, u.y + ti);
      buf[row][SK(i1)] = make_float2(u.x - tr, u.y - ti);
    }
    __syncthreads();
  }
}

// ---------------- fused FFT kernel: STFT pairs + resonance-frame pairs ----------------
__global__ __launch_bounds__(256) void k_fft(const float* __restrict__ audio,
                                             const float* __restrict__ resin,
                                             float* __restrict__ spec,
                                             float* __restrict__ frames) {
  __shared__ float2 buf[2112];    // 2048 + 64 skew pad
  int blk = blockIdx.x;
  if (blk < 2048) {
    int b  = blk >> 6;
    int f0 = (blk & 63) * 2;      // frames f0, f0+1
    for (int j = threadIdx.x; j < 2048; j += 256) {
      float h = 0.5f - 0.5f * __cosf(0.0030679615757712823f * (float)j); // 2pi/2048
      int i1 = f0 * 256 + j;
      int i2 = i1 + 256;
      float a1 = (i1 < 32768) ? audio[b * 32768 + i1] : 0.f;
      float a2 = (i2 < 32768) ? audio[b * 32768 + i2] : 0.f;
      int bi = __brev((unsigned)j) >> 21;
      buf[SK(bi)] = make_float2(a1 * h, a2 * h);
    }
    __syncthreads();
    fft2048_stages(buf, threadIdx.x);
    const float scale = 0.5f * 0.022097086912079608f;  // 0.5 / sqrt(2048)
    for (int k = threadIdx.x; k < 1024; k += 256) {
      float2 zk = buf[SK(k)];
      int kn = (2048 - k) & 2047;
      float2 zn = buf[SK(kn)];
      float f1r = zk.x + zn.x, f1i = zk.y - zn.y;
      float f2r = zk.y + zn.y, f2i = zk.x - zn.x;
      spec[(b * 128 + f0) * 1024 + k]     = sqrtf(f1r * f1r + f1i * f1i) * scale;
      spec[(b * 128 + f0 + 1) * 1024 + k] = sqrtf(f2r * f2r + f2i * f2i) * scale;
    }
  } else {
    int r = blk - 2048;           // 0..511
    int c = r >> 4;
    int g = r & 15;               // frames 2g (exp 2g+1), 2g+1 (exp 2g+2)
    float e1 = (float)(2 * g + 1);
    for (int k = threadIdx.x; k < 2048; k += 256) {
      int kk = (k <= 1024) ? k : 2048 - k;   // Hermitian (real) extension
      float cv = resin[c * 1025 + kk];
      cv = fminf(fmaxf(cv, 0.f), 0.9999f);
      float m1 = __powf(cv, e1);
      float m2 = m1 * cv;
      int bi = __brev((unsigned)k) >> 21;
      buf[SK(bi)] = make_float2(m1, m2);
    }
    __syncthreads();
    fft2048_stages(buf, threadIdx.x);
    for (int j = threadIdx.x; j < 2048; j += 256) {
      float h  = 0.5f - 0.5f * __cosf(0.0030679615757712823f * (float)j);
      float sc = h * (1.f / 2048.f);
      float2 z = buf[SK(j)];
      frames[(c * 32 + 2 * g) * 2048 + j]     = z.x * sc;
      frames[(c * 32 + 2 * g + 1) * 2048 + j] = z.y * sc;
    }
  }
}

// ---------------- weight transposes + chain-weight bf16 hi/lo packs ----------------
__global__ __launch_bounds__(256) void k_prep(const float* __restrict__ Win,
                                              const float* __restrict__ Ws,
                                              const float* __restrict__ Wd,
                                              const float* __restrict__ bwIn,
                                              float* __restrict__ WT,
                                              float* __restrict__ WsT,
                                              float* __restrict__ WdT,
                                              short* __restrict__ Whg,
                                              short* __restrict__ Wlg) {
  int i = blockIdx.x * 256 + threadIdx.x;
  if (i < 32768) { int o = i >> 10, k = i & 1023; WT[k * 32 + o] = Win[i]; }
  if (i < 8192)  { int o2 = i >> 5, m = i & 31;   WsT[m * 256 + o2] = Ws[i]; }
  if (i < 8192)  { int c = i >> 8, o2 = i & 255;  WdT[o2 * 32 + c] = Wd[i]; }
  if (i < 16384) {
    // i = ((s*32+o)*32+m)*2 + w
    int w = i & 1, m = (i >> 1) & 31, o = (i >> 6) & 31, s = i >> 11;
    float val = bwIn[i];
    unsigned bits = __float_as_uint(val);
    float rem = val - __uint_as_float(bits & 0xffff0000u);
    int row = (s * 2 + w) * 32 + o;
    Whg[row * 32 + m] = (short)(bits >> 16);
    Wlg[row * 32 + m] = (short)(__float_as_uint(rem) >> 16);
  }
}

// ---------------- proj_in: h0[b,o,t] = sum_k WT[k][o]*spec[b,t,k] + bias ----------------
__global__ __launch_bounds__(256) void k_proj_in(const float* __restrict__ spec,
                                                 const float* __restrict__ WT,
                                                 const float* __restrict__ bias,
                                                 float* __restrict__ h0) {
  __shared__ float specL[8][1024];
  __shared__ float red[32][8][8];   // [o][tt][p]
  int b  = blockIdx.x >> 4;
  int t0 = (blockIdx.x & 15) * 8;
  for (int i = threadIdx.x; i < 8192; i += 256) {
    int tt = i >> 10, k = i & 1023;
    specL[tt][k] = spec[(b * 128 + t0 + tt) * 1024 + k];
  }
  __syncthreads();
  int o = threadIdx.x & 31, p = threadIdx.x >> 5;
  float part[8] = {0.f,0.f,0.f,0.f,0.f,0.f,0.f,0.f};
  for (int i = 0; i < 128; ++i) {
    int k = p * 128 + ((i + p * 4) & 127);   // stagger: conflict-free banks across p
    float w = WT[k * 32 + o];
#pragma unroll
    for (int tt = 0; tt < 8; ++tt) part[tt] += w * specL[tt][k];
  }
#pragma unroll
  for (int tt = 0; tt < 8; ++tt) red[o][tt][p] = part[tt];
  __syncthreads();
  int oo = threadIdx.x >> 3, tt2 = threadIdx.x & 7;
  float s = bias[oo];
#pragma unroll
  for (int p2 = 0; p2 < 8; ++p2) s += red[oo][tt2][p2];
  h0[b * 4096 + oo * 128 + t0 + tt2] = s;
}

// ---------------- 8-block anticausal chain as per-step MFMA GEMM pairs ----------------
__global__ __launch_bounds__(1024) void k_chain(const float* __restrict__ h0,
                                                const short* __restrict__ Whg,
                                                const short* __restrict__ Wlg,
                                                const float* __restrict__ bb,
                                                float* __restrict__ accout) {
  __shared__ __align__(16) short Hh[192 * 40];   // rows stride 40 bf16 (80 B)
  __shared__ __align__(16) short Hl[192 * 40];
  __shared__ float Hf[128 * 33];                 // fp32 H for exact residual
  __shared__ float bL[256];
  __shared__ float red[16];
  int b = blockIdx.x, tid = threadIdx.x;

  for (int i = tid; i < 4096; i += 1024) {
    int t = i & 127;                 // h0 layout [o][t]
    int o = i >> 7;
    float val = h0[b * 4096 + i];
    Hf[t * 33 + o] = val;
    unsigned bits = __float_as_uint(val);
    float rem = val - __uint_as_float(bits & 0xffff0000u);
    Hh[t * 40 + o] = (short)(bits >> 16);
    Hl[t * 40 + o] = (short)(__float_as_uint(rem) >> 16);
  }
  for (int i = tid; i < 64 * 40; i += 1024) {    // zero pad rows 128..191
    Hh[128 * 40 + i] = 0;
    Hl[128 * 40 + i] = 0;
  }
  if (tid < 256) bL[tid] = bb[tid];
  __syncthreads();

  int wave = tid >> 6, lane = tid & 63;
  int quad = lane >> 4, l15 = lane & 15;
  int t0 = (wave & 7) * 16, o0 = (wave >> 3) * 16;
  int tD = t0 + quad * 4;          // D rows tD..tD+3
  int oD = o0 + l15;               // D col

  const bf16x8* Hh8 = (const bf16x8*)Hh;   // unit = row*5 + quad (40 bf16 = 5 units)
  const bf16x8* Hl8 = (const bf16x8*)Hl;
  const bf16x8* Wh8 = (const bf16x8*)Whg;  // unit = row*4 + quad (32 bf16 = 4 units)
  const bf16x8* Wl8 = (const bf16x8*)Wlg;

  float accsum[4] = {0.f, 0.f, 0.f, 0.f};
  const int DIL[8] = {1, 2, 4, 8, 16, 32, 64, 1};

#pragma unroll
  for (int s = 0; s < 8; ++s) {
    int arow = t0 + l15;
    int frow = arow + DIL[s];        // <= 191, pad rows give zeros
    bf16x8 Ah = Hh8[arow * 5 + quad];
    bf16x8 Al = Hl8[arow * 5 + quad];
    bf16x8 Fh = Hh8[frow * 5 + quad];
    bf16x8 Fl = Hl8[frow * 5 + quad];
    int w0row = ((s * 2 + 0) * 32 + oD) * 4 + quad;
    int w1row = ((s * 2 + 1) * 32 + oD) * 4 + quad;
    bf16x8 B0h = Wh8[w0row], B0l = Wl8[w0row];
    bf16x8 B1h = Wh8[w1row], B1l = Wl8[w1row];
    float bias = bL[s * 32 + oD];
    f32x4 acc = {bias, bias, bias, bias};
    MFMA16(acc, Ah, B0h); MFMA16(acc, Ah, B0l); MFMA16(acc, Al, B0h);
    MFMA16(acc, Fh, B1h); MFMA16(acc, Fh, B1l); MFMA16(acc, Fl, B1h);
    float hnew[4], lmax = 0.f;
#pragma unroll
    for (int r = 0; r < 4; ++r) {
      float sv = acc[r];
      sv = (sv > 0.f) ? sv : 0.2f * sv;       // leaky_relu 0.2
      sv += Hf[(tD + r) * 33 + oD];           // residual (exact fp32)
      hnew[r] = sv;
      lmax = fmaxf(lmax, fabsf(sv));
    }
#pragma unroll
    for (int off = 32; off > 0; off >>= 1)
      lmax = fmaxf(lmax, __shfl_down(lmax, off, 64));
    if (lane == 0) red[wave] = lmax;
    __syncthreads();                 // red visible; all H reads of this step done
    float mx = red[0];
#pragma unroll
    for (int i = 1; i < 16; ++i) mx = fmaxf(mx, red[i]);
    float nm = 1.f / (mx + 1e-8f);
#pragma unroll
    for (int r = 0; r < 4; ++r) {
      float hv = hnew[r] * nm;
      accsum[r] += hv;
      int t = tD + r;
      Hf[t * 33 + oD] = hv;
      unsigned bits = __float_as_uint(hv);
      float rem = hv - __uint_as_float(bits & 0xffff0000u);
      Hh[t * 40 + oD] = (short)(bits >> 16);
      Hl[t * 40 + oD] = (short)(__float_as_uint(rem) >> 16);
    }
    __syncthreads();                 // new H visible for next step
  }
#pragma unroll
  for (int r = 0; r < 4; ++r)
    accout[b * 4096 + (tD + r) * 32 + oD] = accsum[r];
}

// ---------------- sparse (relu proj 32->256, to d_out) + dense (256->32, to ws) ----------------
__global__ __launch_bounds__(256) void k_sparse_dense(const float* __restrict__ acc,
                                                      const float* __restrict__ WsT,
                                                      const float* __restrict__ bs,
                                                      const float* __restrict__ WdT,
                                                      const float* __restrict__ bd,
                                                      float* __restrict__ out_sparse,
                                                      float* __restrict__ v) {
  __shared__ float accL[32];
  __shared__ float sL[256];
  __shared__ float red[8][32];
  int b = blockIdx.x >> 7, t = blockIdx.x & 127;
  int tid = threadIdx.x;
  if (tid < 32) accL[tid] = acc[b * 4096 + t * 32 + tid];
  __syncthreads();
  float s = bs[tid];
  for (int m = 0; m < 32; ++m) s += WsT[m * 256 + tid] * accL[m];
  s = fmaxf(s, 0.f);
  out_sparse[b * 32768 + tid * 128 + t] = s;
  sL[tid] = s;
  __syncthreads();
  int c = tid & 31, p = tid >> 5;
  float part = 0.f;
  for (int j = 0; j < 32; ++j) {
    int o2 = p * 32 + j;
    part += WdT[o2 * 32 + c] * sL[o2];
  }
  red[p][c] = part;
  __syncthreads();
  if (tid < 32) {
    float vv = bd[tid];
    for (int p2 = 0; p2 < 8; ++p2) vv += red[p2][tid];
    v[b * 4096 + tid * 128 + t] = vv;
  }
}

// ---------------- R spectrum: overlap-add (fused) + 256-pt FFT along u ----------------
// Block = (c, 16-r group): 512 blocks, 33 KB LDS -> 2+ blocks/CU.
// Rr/Ri[(k*32+c)*256 + r], k in [0,129) (Hermitian: input real).
__global__ __launch_bounds__(256) void k_rfft(const float* __restrict__ frames,
                                              float* __restrict__ Rr,
                                              float* __restrict__ Ri) {
  __shared__ float2 buf[16][264];   // skewed cols
  int c = blockIdx.x >> 4, rg = blockIdx.x & 15;
  for (int t = threadIdx.x; t < 2048; t += 256) {
    int u = t >> 4, rr = t & 15;    // u in [0,128)
    int s = u * 256 + rg * 16 + rr;
    int g = s >> 10, j0 = s & 1023;
    float val = frames[(c * 32 + g) * 2048 + j0];
    if (g > 0) val += frames[(c * 32 + g - 1) * 2048 + j0 + 1024];
    int bi = __brev((unsigned)u) >> 24;      // even for u<128
    buf[rr][SK(bi)]     = make_float2(val, 0.f);
    buf[rr][SK(bi) + 1] = make_float2(0.f, 0.f);   // SK(bi|1)=SK(bi)+1 (bi even)
  }
  __syncthreads();
  fft256_rows<16>(buf, threadIdx.x, -1.f);
  for (int t = threadIdx.x; t < 129 * 16; t += 256) {
    int k = t >> 4, rr = t & 15;
    int idx = (k * 32 + c) * 256 + rg * 16 + rr;
    float2 z = buf[rr][SK(k)];
    Rr[idx] = z.x;
    Ri[idx] = z.y;
  }
}

// ---------------- V spectrum: 256-pt FFT of v[b,c,:] (zero-padded) ----------------
// Block = (b, c-half). Vr/Vi[(k*32+b)*32 + c], k in [0,129).
__global__ __launch_bounds__(256) void k_vfft(const float* __restrict__ v,
                                              float* __restrict__ Vr,
                                              float* __restrict__ Vi) {
  __shared__ float2 buf[16][264];
  int b = blockIdx.x >> 1, ch = blockIdx.x & 1;
  for (int t = threadIdx.x; t < 2048; t += 256) {
    int c2 = t >> 7, u = t & 127;
    float val = v[b * 4096 + (ch * 16 + c2) * 128 + u];
    int bi = __brev((unsigned)u) >> 24;
    buf[c2][SK(bi)]     = make_float2(val, 0.f);
    buf[c2][SK(bi) + 1] = make_float2(0.f, 0.f);
  }
  __syncthreads();
  fft256_rows<16>(buf, threadIdx.x, -1.f);
  for (int t = threadIdx.x; t < 129 * 16; t += 256) {
    int k = t >> 4, c2 = t & 15;
    int idx = (k * 32 + b) * 32 + ch * 16 + c2;
    float2 z = buf[c2][SK(k)];
    Vr[idx] = z.x;
    Vi[idx] = z.y;
  }
}

// ---------------- per-frequency complex GEMM: Y[b,r] = sum_c V[b,c] * R[c,r] ----------------
// Block = (k, r-quarter): 516 blocks. V tile in LDS (wave-uniform broadcast
// reads); R streamed coalesced (64 consecutive r per wave); thread owns 8 b x 1 r.
__global__ __launch_bounds__(256) void k_cgemm(const float* __restrict__ Vr,
                                               const float* __restrict__ Vi,
                                               const float* __restrict__ Rr,
                                               const float* __restrict__ Ri,
                                               float* __restrict__ Yr,
                                               float* __restrict__ Yi) {
  __shared__ float2 Vs[32][32];     // 8 KB
  int k = blockIdx.x >> 2, rq = blockIdx.x & 3;
  for (int t = threadIdx.x; t < 1024; t += 256)
    Vs[t >> 5][t & 31] = make_float2(Vr[k * 1024 + t], Vi[k * 1024 + t]);
  __syncthreads();
  int lane = threadIdx.x & 63, bg = threadIdx.x >> 6;
  int r = rq * 64 + lane;
  float yre[8], yim[8];
#pragma unroll
  for (int i = 0; i < 8; ++i) { yre[i] = 0.f; yim[i] = 0.f; }
  for (int c = 0; c < 32; ++c) {
    float rrv = Rr[(k * 32 + c) * 256 + r];
    float riv = Ri[(k * 32 + c) * 256 + r];
#pragma unroll
    for (int i = 0; i < 8; ++i) {
      float2 vc = Vs[bg * 8 + i][c];   // wave-uniform -> LDS broadcast
      yre[i] += vc.x * rrv - vc.y * riv;
      yim[i] += vc.x * riv + vc.y * rrv;
    }
  }
#pragma unroll
  for (int i = 0; i < 8; ++i) {
    int b = bg * 8 + i;
    Yr[(k * 32 + b) * 256 + r] = yre[i];
    Yi[(k * 32 + b) * 256 + r] = yim[i];
  }
}

// ---------------- inverse 256-pt FFT over k -> y (writes EVERY y element once) ----------------
// Block = (b, 16-r group): 512 blocks. Hermitian reconstruction for k in (128,256).
__global__ __launch_bounds__(256) void k_yifft(const float* __restrict__ Yr,
                                               const float* __restrict__ Yi,
                                               float* __restrict__ y) {
  __shared__ float2 buf[16][264];
  int b = blockIdx.x >> 4, rg = blockIdx.x & 15;
  int r0 = rg * 16;
  for (int t = threadIdx.x; t < 4096; t += 256) {
    int k = t >> 4, rr = t & 15;
    float re, im;
    if (k <= 128) {
      re = Yr[(k * 32 + b) * 256 + r0 + rr];
      im = Yi[(k * 32 + b) * 256 + r0 + rr];
    } else {
      int kk = 256 - k;
      re =  Yr[(kk * 32 + b) * 256 + r0 + rr];
      im = -Yi[(kk * 32 + b) * 256 + r0 + rr];
    }
    int bi = __brev((unsigned)k) >> 24;
    buf[rr][SK(bi)] = make_float2(re, im);
  }
  __syncthreads();
  fft256_rows<16>(buf, threadIdx.x, 1.f);    // inverse butterflies
  const float inv = 1.f / 256.f;
  for (int t = threadIdx.x; t < 2048; t += 256) {
    int q = t >> 4, rr = t & 15;
    y[b * 32768 + q * 256 + r0 + rr] = buf[rr][SK(q)].x * inv;
  }
}

extern "C" void kernel_launch(void* const* d_in, const int* in_sizes, int n_in,
                              void* d_out, int out_size, void* d_ws, size_t ws_size,
                              hipStream_t stream) {
  const float* audio = (const float*)d_in[0];
  const float* Win   = (const float*)d_in[1];
  const float* bin   = (const float*)d_in[2];
  const float* bw    = (const float*)d_in[3];
  const float* bb    = (const float*)d_in[4];
  const float* Ws    = (const float*)d_in[5];
  const float* bs    = (const float*)d_in[6];
  const float* Wd    = (const float*)d_in[7];
  const float* bd    = (const float*)d_in[8];
  const float* reson = (const float*)d_in[9];

  float* out = (float*)d_out;           // [0,1048576) = y ; [1048576,2097152) = sparse
  float* ws  = (float*)d_ws;

  float* spec   = ws + WS_SPEC;
  float* h0     = ws + WS_H0;
  float* accb   = ws + WS_ACC;
  float* vbuf   = ws + WS_V;
  float* WT     = ws + WS_WTIN;
  float* WsT    = ws + WS_WST;
  float* WdT    = ws + WS_WDT;
  float* frames = ws + WS_FRAMES;
  // chain-weight packs live in WS_V until k_sparse_dense overwrites it (after k_chain)
  short* Whg = (short*)(ws + WS_V);                // 16384 bf16 = 32 KB
  short* Wlg = (short*)(ws + WS_V + 8192u);        // 16384 bf16 = 32 KB
  // FFT-conv buffers in the spec region (dead after k_proj_in) + frames region
  float* Rr = ws + WS_RR;
  float* Ri = ws + WS_RI;
  float* Vr = ws + WS_VR;
  float* Vi = ws + WS_VI;
  float* Yr = ws + WS_YR;
  float* Yi = ws + WS_YI;   // frames region, dead after k_rfft

  k_prep<<<128, 256, 0, stream>>>(Win, Ws, Wd, bw, WT, WsT, WdT, Whg, Wlg);
  k_fft<<<2560, 256, 0, stream>>>(audio, reson, spec, frames);
  k_proj_in<<<512, 256, 0, stream>>>(spec, WT, bin, h0);
  k_rfft<<<512, 256, 0, stream>>>(frames, Rr, Ri);          // spec region now free
  k_chain<<<32, 1024, 0, stream>>>(h0, Whg, Wlg, bb, accb);
  k_sparse_dense<<<4096, 256, 0, stream>>>(accb, WsT, bs, WdT, bd, out + 1048576, vbuf);
  k_vfft<<<64, 256, 0, stream>>>(vbuf, Vr, Vi);
  k_cgemm<<<516, 256, 0, stream>>>(Vr, Vi, Rr, Ri, Yr, Yi);
  k_yifft<<<512, 256, 0, stream>>>(Yr, Yi, out);            // writes all of y: no memset
}